// Round 8
// baseline (647.699 us; speedup 1.0000x reference)
//
#include <hip/hip_runtime.h>
#include <float.h>

#define DECAY 0.99f
#define EPS 1e-5f
#define NROWS 65536
#define DIM 256
#define NEMB 1024
#define CH 64            // rows per sub-chunk in segmented reduction
#define MAXSUB 2048      // NROWS/CH + NEMB upper bound on total sub-chunks

typedef _Float16 f16;
typedef _Float16 half8 __attribute__((ext_vector_type(8)));
typedef float f32x4 __attribute__((ext_vector_type(4)));

// ---------- K0a: ||e_k||^2 per code + zero counts ----------
__global__ __launch_bounds__(256) void k_enorm(const float* __restrict__ embed,
                                               float* __restrict__ enorm2,
                                               int* __restrict__ counts) {
    int kk = threadIdx.x & 63;
    int dg = threadIdx.x >> 6;              // 0..3
    int k  = blockIdx.x * 64 + kk;          // 16 blocks * 64 = 1024 codes
    float s = 0.f;
    for (int d = dg; d < DIM; d += 4) {
        float v = embed[(size_t)d * NEMB + k];
        s = fmaf(v, v, s);
    }
    __shared__ float red[4][64];
    red[dg][kk] = s;
    __syncthreads();
    if (dg == 0) enorm2[k] = red[0][kk] + red[1][kk] + red[2][kk] + red[3][kk];
    int gt = blockIdx.x * 256 + threadIdx.x;
    if (gt < NEMB) counts[gt] = 0;
}

// ---------- K0b: fused transpose (embedT fp32) + hi/lo split (ehlT f16) ----------
__global__ __launch_bounds__(256) void k_prep(const float* __restrict__ embed,
                                              float* __restrict__ embedT,
                                              f16* __restrict__ ehlT) {
    __shared__ float tile[32][33];           // [d-local][c-local]
    int c0 = blockIdx.x * 32, d0 = blockIdx.y * 32;
    int tx = threadIdx.x, ty = threadIdx.y;  // 32 x 8
#pragma unroll
    for (int i = 0; i < 4; i++)
        tile[ty + 8 * i][tx] = embed[(size_t)(d0 + ty + 8 * i) * NEMB + c0 + tx];
    __syncthreads();
#pragma unroll
    for (int i = 0; i < 4; i++) {
        int c = c0 + ty + 8 * i;
        int d = d0 + tx;
        float v = tile[tx][ty + 8 * i];
        embedT[(size_t)c * DIM + d] = v;
        f16 h = (f16)v;
        ehlT[(size_t)c * 512 + d]       = h;
        ehlT[(size_t)c * 512 + 256 + d] = (f16)(v - (float)h);
    }
}

// ---------- K1: MFMA GEMM-argmin v6: A LDS-resident, B global->reg, NO K-loop barriers ----------
// 512 threads = 8 waves (2 row x 4 col), block = 128 rows x 1024 cols (4 slabs of 256).
// A resident: [128 rows][512 f16] = 128KB, byte = row*1024 + ((slot*16)^((row&7)<<4)).
// B fragments read directly from ehlT (1MB, L2-resident): 4 loop-invariant base
// pointers per wave + uniform per-kt offset -> immediate-folded loads.
// K order per slab: kt 0-7 xh*eh, 8-15 xl*eh, 16-23 xh*el (effective K=768).
#define LDS_A  0         // 128KB
#define LDS_PV 131072    // float[128][4]
#define LDS_PI 133120    // int[128][4]
#define LDS_SZ 135168

__global__ __launch_bounds__(512, 2) void k_argmin_mfma(const float* __restrict__ input,
                                                        const f16* __restrict__ ehlT,
                                                        const float* __restrict__ enorm2,
                                                        int* __restrict__ ind,
                                                        float* __restrict__ out_ind,
                                                        int* __restrict__ counts) {
    __shared__ char lds[LDS_SZ];
    const int tid  = threadIdx.x;
    const int lane = tid & 63;
    const int w    = tid >> 6;        // wave 0..7
    const int wr   = w >> 2;          // 0/1 : rows wr*64..+64
    const int wc   = w & 3;          // 0..3: cols wc*64..+64 within 256-slab
    const int rb   = blockIdx.x * 128;
    const int l15  = lane & 15;
    const int lkh  = lane >> 4;       // 0..3
    const int swa  = (l15 & 7) << 4;

    // ---- stage A once: 128 rows x 256 d fp32 -> hi/lo f16, swizzled LDS ----
#pragma unroll
    for (int it8 = 0; it8 < 4; it8++) {
        int task = tid + 512 * it8;          // 0..2047
        int row = task >> 4, ch = task & 15; // ch = 16-d chunk
        const float4* g = (const float4*)(input + (size_t)(rb + row) * DIM + ch * 16);
        float fv[16];
        *(float4*)(fv + 0)  = g[0];
        *(float4*)(fv + 4)  = g[1];
        *(float4*)(fv + 8)  = g[2];
        *(float4*)(fv + 12) = g[3];
        half8 hh[2], llv[2];
#pragma unroll
        for (int u = 0; u < 2; u++)
#pragma unroll
            for (int e = 0; e < 8; e++) {
                float x = fv[u * 8 + e];
                f16 h = (f16)x;
                hh[u][e]  = h;
                llv[u][e] = (f16)(x - (float)h);
            }
        int rbase = row * 1024;
        int sw = (row & 7) << 4;
        *(half8*)(lds + LDS_A + rbase + (((ch * 2    ) * 16) ^ sw)) = hh[0];
        *(half8*)(lds + LDS_A + rbase + (((ch * 2 + 1) * 16) ^ sw)) = hh[1];
        *(half8*)(lds + LDS_A + rbase + (((32 + ch * 2) * 16) ^ sw)) = llv[0];
        *(half8*)(lds + LDS_A + rbase + (((33 + ch * 2) * 16) ^ sw)) = llv[1];
    }
    __syncthreads();   // the ONLY barrier before the final reduce

    float bv[16];
    int   bi[16];
#pragma unroll
    for (int q = 0; q < 16; q++) { bv[q] = FLT_MAX; bi[q] = 0x7fffffff; }

    for (int ct = 0; ct < 4; ct++) {
        const int cb = ct * 256;
        // loop-invariant B fragment base pointers (include lane parts)
        const f16* bp0 = ehlT + (size_t)(cb + wc * 64 +  0 + l15) * 512 + lkh * 8;
        const f16* bp1 = ehlT + (size_t)(cb + wc * 64 + 16 + l15) * 512 + lkh * 8;
        const f16* bp2 = ehlT + (size_t)(cb + wc * 64 + 32 + l15) * 512 + lkh * 8;
        const f16* bp3 = ehlT + (size_t)(cb + wc * 64 + 48 + l15) * 512 + lkh * 8;

        f32x4 acc[4][4];
#pragma unroll
        for (int fr = 0; fr < 4; fr++)
#pragma unroll
            for (int fc = 0; fc < 4; fc++) acc[fr][fc] = (f32x4){0.f, 0.f, 0.f, 0.f};

#pragma unroll
        for (int kt = 0; kt < 24; kt++) {
            const int seg = kt >> 3, kq = kt & 7;
            const int boff = ((seg == 2) ? 256 : 0) + kq * 32;   // uniform per kt
            half8 bf[4];
            bf[0] = *(const half8*)(bp0 + boff);
            bf[1] = *(const half8*)(bp1 + boff);
            bf[2] = *(const half8*)(bp2 + boff);
            bf[3] = *(const half8*)(bp3 + boff);
            const int jslot = ((seg == 1) ? 32 : 0) + kq * 4 + lkh;
            const int koff = (jslot * 16) ^ swa;
            half8 af[4];
#pragma unroll
            for (int f = 0; f < 4; f++) {
                int row = wr * 64 + f * 16 + l15;
                af[f] = *(const half8*)(lds + LDS_A + row * 1024 + koff);
            }
#pragma unroll
            for (int fr = 0; fr < 4; fr++)
#pragma unroll
                for (int fc = 0; fc < 4; fc++)
                    acc[fr][fc] = __builtin_amdgcn_mfma_f32_16x16x32_f16(
                        af[fr], bf[fc], acc[fr][fc], 0, 0, 0);
        }

        // ---- slab epilogue: running per-row argmin ----
#pragma unroll
        for (int fc = 0; fc < 4; fc++) {
            int col = cb + wc * 64 + fc * 16 + l15;
            float e2 = enorm2[col];
#pragma unroll
            for (int fr = 0; fr < 4; fr++)
#pragma unroll
                for (int r = 0; r < 4; r++) {
                    float s = fmaf(-2.f, acc[fr][fc][r], e2);
                    int q = fr * 4 + r;
                    if (s < bv[q]) { bv[q] = s; bi[q] = col; }
                }
        }
    }

    // ---- cross-lane reduce: min over the 16 col-lanes (same lkh group) ----
#pragma unroll
    for (int q = 0; q < 16; q++) {
        float v = bv[q]; int i = bi[q];
#pragma unroll
        for (int m = 1; m <= 8; m <<= 1) {
            float ov = __shfl_xor(v, m, 64);
            int   oi = __shfl_xor(i, m, 64);
            if (ov < v || (ov == v && oi < i)) { v = ov; i = oi; }
        }
        bv[q] = v; bi[q] = i;
    }
    float* PV = (float*)(lds + LDS_PV);          // [128][4]
    int*   PI = (int*)(lds + LDS_PI);            // [128][4]
    if (l15 == 0) {
#pragma unroll
        for (int fr = 0; fr < 4; fr++)
#pragma unroll
            for (int r = 0; r < 4; r++) {
                int rrow = wr * 64 + fr * 16 + lkh * 4 + r;
                PV[rrow * 4 + wc] = bv[fr * 4 + r];
                PI[rrow * 4 + wc] = bi[fr * 4 + r];
            }
    }
    __syncthreads();
    if (tid < 128) {
        float best = FLT_MAX; int bidx = 0x7fffffff;
#pragma unroll
        for (int t = 0; t < 4; t++) {
            float v = PV[tid * 4 + t];
            int   i = PI[tid * 4 + t];
            if (v < best || (v == best && i < bidx)) { best = v; bidx = i; }
        }
        ind[rb + tid] = bidx;
        out_ind[rb + tid] = (float)bidx;
        atomicAdd(&counts[bidx], 1);    // fused histogram (wave-coalesced by compiler)
    }
}

// ---------- K2: quantize_st output + per-block diff partials ----------
__global__ __launch_bounds__(256) void k_quant(const float* __restrict__ input,
                                               const float* __restrict__ embedT,
                                               const int* __restrict__ ind,
                                               float* __restrict__ out_q,
                                               float* __restrict__ partials) {
    const int tid = threadIdx.x;
    const unsigned gid = blockIdx.x * 256 + tid;
    float s = 0.f;
#pragma unroll
    for (int j = 0; j < 8; j++) {
        size_t i4 = (size_t)gid + (size_t)j * 524288u;   // 4194304 float4 total
        int row = (int)(i4 >> 6);
        int d4  = (int)(i4 & 63);
        float4 iv = *reinterpret_cast<const float4*>(input + i4 * 4);
        int k = ind[row];
        float4 qv = *reinterpret_cast<const float4*>(embedT + (size_t)k * DIM + d4 * 4);
        float dx = qv.x - iv.x, dy = qv.y - iv.y, dz = qv.z - iv.z, dw = qv.w - iv.w;
        float4 ov;
        ov.x = iv.x + dx; ov.y = iv.y + dy; ov.z = iv.z + dz; ov.w = iv.w + dw;
        *reinterpret_cast<float4*>(out_q + i4 * 4) = ov;
        s += dx * dx + dy * dy + dz * dz + dw * dw;
    }
    __shared__ float red[256];
    red[tid] = s;
    __syncthreads();
    for (int off = 128; off > 0; off >>= 1) {
        if (tid < off) red[tid] += red[tid + off];
        __syncthreads();
    }
    if (tid == 0) partials[blockIdx.x] = red[0];
}

// ---------- K4: diff finalize + scans + ncs, n, cs ----------
__global__ __launch_bounds__(1024) void k_scan(const int* __restrict__ counts,
                                               const float* __restrict__ cluster_size,
                                               const float* __restrict__ qpartials,
                                               int* __restrict__ offsets,
                                               int* __restrict__ cursor,
                                               int* __restrict__ substart,
                                               float* __restrict__ out_ncs,
                                               float* __restrict__ cs,
                                               float* __restrict__ out_diff) {
    __shared__ int sh[NEMB];
    __shared__ float shf[NEMB];
    int tid = threadIdx.x;
    // ---- diff finalize (was k_diff) ----
    shf[tid] = qpartials[tid] + qpartials[tid + 1024];
    __syncthreads();
    for (int off = 512; off > 0; off >>= 1) {
        if (tid < off) shf[tid] += shf[tid + off];
        __syncthreads();
    }
    if (tid == 0) out_diff[0] = shf[0] / 16777216.0f;
    __syncthreads();
    // ---- scans ----
    int c = counts[tid];
    sh[tid] = c;
    __syncthreads();
    for (int off = 1; off < NEMB; off <<= 1) {
        int t = (tid >= off) ? sh[tid - off] : 0;
        __syncthreads();
        sh[tid] += t;
        __syncthreads();
    }
    int excl = sh[tid] - c;
    offsets[tid] = excl;
    cursor[tid]  = excl;
    int sc = (c + CH - 1) / CH;
    __syncthreads();
    sh[tid] = sc;
    __syncthreads();
    for (int off = 1; off < NEMB; off <<= 1) {
        int t = (tid >= off) ? sh[tid - off] : 0;
        __syncthreads();
        sh[tid] += t;
        __syncthreads();
    }
    substart[tid] = sh[tid] - sc;
    if (tid == NEMB - 1) substart[NEMB] = sh[tid];
    float ncs = cluster_size[tid] * DECAY + (1.f - DECAY) * (float)c;
    out_ncs[tid] = ncs;
    shf[tid] = ncs;
    __syncthreads();
    for (int off = 512; off > 0; off >>= 1) {
        if (tid < off) shf[tid] += shf[tid + off];
        __syncthreads();
    }
    float n = shf[0];
    cs[tid] = (ncs + EPS) / (n + NEMB * EPS) * n;
}

// ---------- K5: scatter rows by cluster ----------
__global__ __launch_bounds__(256) void k_scatter(const int* __restrict__ ind,
                                                 int* __restrict__ cursor,
                                                 int* __restrict__ sorted) {
    int i = blockIdx.x * 256 + threadIdx.x;
    int k = ind[i];
    int pos = atomicAdd(&cursor[k], 1);
    sorted[pos] = i;
}

// ---------- K6a: balanced partial sums. block = one 64-row sub-chunk ----------
__global__ __launch_bounds__(256) void k_psum(const float* __restrict__ input,
                                              const int* __restrict__ sorted,
                                              const int* __restrict__ counts,
                                              const int* __restrict__ offsets,
                                              const int* __restrict__ substart,
                                              float* __restrict__ partial) {
    const int b = blockIdx.x;
    if (b >= substart[NEMB]) return;
    int lo = 0, hi = NEMB;
    while (hi - lo > 1) {
        int mid = (lo + hi) >> 1;
        if (substart[mid] <= b) lo = mid; else hi = mid;
    }
    const int k     = lo;
    const int chunk = b - substart[k];
    const int cnt   = counts[k];
    const int base  = offsets[k] + chunk * CH;
    const int lim   = min(CH, cnt - chunk * CH);
    const int d     = threadIdx.x;
    float s = 0.f;
    for (int i = 0; i < lim; i++) {
        int row = sorted[base + i];
        s += input[(size_t)row * DIM + d];
    }
    partial[(size_t)b * DIM + d] = s;
}

// ---------- K6b: per-cluster combine (fixed order) + EMA + new_embed ----------
__global__ __launch_bounds__(256) void k_ema(const float* __restrict__ partial,
                                             const float* __restrict__ embed_avg,
                                             const int* __restrict__ substart,
                                             const float* __restrict__ cs,
                                             float* __restrict__ out_navg,
                                             float* __restrict__ out_nembed) {
    const int d = blockIdx.x;
    const int t = threadIdx.x;
#pragma unroll
    for (int i = 0; i < 4; i++) {
        int k = t + 256 * i;
        int s0 = substart[k], s1 = substart[k + 1];
        float s = 0.f;
        for (int sub = s0; sub < s1; sub++)
            s += partial[(size_t)sub * DIM + d];
        float navg = embed_avg[(size_t)d * NEMB + k] * (DECAY * DECAY) + (1.f - DECAY) * s;
        out_navg[(size_t)d * NEMB + k] = navg;
        out_nembed[(size_t)d * NEMB + k] = navg / cs[k];
    }
}

extern "C" void kernel_launch(void* const* d_in, const int* in_sizes, int n_in,
                              void* d_out, int out_size, void* d_ws, size_t ws_size,
                              hipStream_t stream) {
    const float* input        = (const float*)d_in[0];
    const float* embed        = (const float*)d_in[1];
    const float* cluster_size = (const float*)d_in[2];
    const float* embed_avg    = (const float*)d_in[3];

    float* out        = (float*)d_out;
    float* out_q      = out;                       // 16777216
    float* out_diff   = out + 16777216;            // 1
    float* out_ind    = out + 16777217;            // 65536
    float* out_ncs    = out + 16842753;            // 1024
    float* out_navg   = out + 16843777;            // 262144
    float* out_nembed = out + 17105921;            // 262144

    char* ws = (char*)d_ws;
    size_t o = 0;
    int*   w_ind      = (int*)(ws + o);   o += (size_t)NROWS * 4;
    float* w_embedT   = (float*)(ws + o); o += (size_t)DIM * NEMB * 4;
    float* w_enorm    = (float*)(ws + o); o += NEMB * 4;
    int*   w_counts   = (int*)(ws + o);   o += NEMB * 4;
    int*   w_offsets  = (int*)(ws + o);   o += NEMB * 4;
    int*   w_cursor   = (int*)(ws + o);   o += NEMB * 4;
    float* w_cs       = (float*)(ws + o); o += NEMB * 4;
    float* w_partials = (float*)(ws + o); o += 2048 * 4;
    int*   w_sorted   = (int*)(ws + o);   o += (size_t)NROWS * 4;
    int*   w_substart = (int*)(ws + o);   o += (NEMB + 4) * 4;
    float* w_partial  = (float*)(ws + o); o += (size_t)MAXSUB * DIM * 4;
    f16*   w_ehlT     = (f16*)(ws + o);   o += (size_t)NEMB * 512 * 2;

    k_enorm<<<16, 256, 0, stream>>>(embed, w_enorm, w_counts);
    k_prep<<<dim3(32, 8), dim3(32, 8), 0, stream>>>(embed, w_embedT, w_ehlT);
    k_argmin_mfma<<<NROWS / 128, 512, 0, stream>>>(input, w_ehlT, w_enorm,
                                                   w_ind, out_ind, w_counts);
    k_quant<<<2048, 256, 0, stream>>>(input, w_embedT, w_ind, out_q, w_partials);
    k_scan<<<1, 1024, 0, stream>>>(w_counts, cluster_size, w_partials, w_offsets,
                                   w_cursor, w_substart, out_ncs, w_cs, out_diff);
    k_scatter<<<NROWS / 256, 256, 0, stream>>>(w_ind, w_cursor, w_sorted);
    k_psum<<<MAXSUB, 256, 0, stream>>>(input, w_sorted, w_counts, w_offsets,
                                       w_substart, w_partial);
    k_ema<<<DIM, 256, 0, stream>>>(w_partial, embed_avg, w_substart, w_cs,
                                   out_navg, out_nembed);
}

// Round 9
// 309.255 us; speedup vs baseline: 2.0944x; 2.0944x over previous
//
#include <hip/hip_runtime.h>
#include <float.h>

#define DECAY 0.99f
#define EPS 1e-5f
#define NROWS 65536
#define DIM 256
#define NEMB 1024
#define CH 64            // rows per sub-chunk in segmented reduction
#define MAXSUB 2048      // NROWS/CH + NEMB upper bound on total sub-chunks

#define GLOBAL_AS __attribute__((address_space(1)))
#define LOCAL_AS  __attribute__((address_space(3)))

typedef _Float16 f16;
typedef _Float16 half8 __attribute__((ext_vector_type(8)));
typedef float f32x4 __attribute__((ext_vector_type(4)));

// ---------- K0a: ||e_k||^2 per code + zero counts ----------
__global__ __launch_bounds__(256) void k_enorm(const float* __restrict__ embed,
                                               float* __restrict__ enorm2,
                                               int* __restrict__ counts) {
    int kk = threadIdx.x & 63;
    int dg = threadIdx.x >> 6;              // 0..3
    int k  = blockIdx.x * 64 + kk;          // 16 blocks * 64 = 1024 codes
    float s = 0.f;
    for (int d = dg; d < DIM; d += 4) {
        float v = embed[(size_t)d * NEMB + k];
        s = fmaf(v, v, s);
    }
    __shared__ float red[4][64];
    red[dg][kk] = s;
    __syncthreads();
    if (dg == 0) enorm2[k] = red[0][kk] + red[1][kk] + red[2][kk] + red[3][kk];
    int gt = blockIdx.x * 256 + threadIdx.x;
    if (gt < NEMB) counts[gt] = 0;
}

// ---------- K0b: fused transpose (embedT fp32) + hi/lo split (ehlT f16) ----------
__global__ __launch_bounds__(256) void k_prep(const float* __restrict__ embed,
                                              float* __restrict__ embedT,
                                              f16* __restrict__ ehlT) {
    __shared__ float tile[32][33];           // [d-local][c-local]
    int c0 = blockIdx.x * 32, d0 = blockIdx.y * 32;
    int tx = threadIdx.x, ty = threadIdx.y;  // 32 x 8
#pragma unroll
    for (int i = 0; i < 4; i++)
        tile[ty + 8 * i][tx] = embed[(size_t)(d0 + ty + 8 * i) * NEMB + c0 + tx];
    __syncthreads();
#pragma unroll
    for (int i = 0; i < 4; i++) {
        int c = c0 + ty + 8 * i;
        int d = d0 + tx;
        float v = tile[tx][ty + 8 * i];
        embedT[(size_t)c * DIM + d] = v;
        f16 h = (f16)v;
        ehlT[(size_t)c * 512 + d]       = h;
        ehlT[(size_t)c * 512 + 256 + d] = (f16)(v - (float)h);
    }
}

// ---------- K1: MFMA GEMM-argmin v7 = R6 structure + counted-vmcnt raw barriers ----------
// 512 threads = 8 waves (2 row x 4 col), block = 128 rows x 1024 cols (4 slabs of 256).
// A resident: [128 rows][512 f16] = 128KB, byte = row*1024 + ((slot*16)^((row&7)<<4)).
// B: double-buffered 16KB tiles (256 cols x 32 k), filled by global_load_lds
//    (linear dest, pre-swizzled per-lane source: slot_log = (l&3)^((l>>3)&3)),
//    read at byte = col*64 + ((lkh*16) ^ (((col>>1)&3)<<4)).
// Per K-step: issue 2 loads (tile it+1 -> buf^1); s_waitcnt vmcnt(2) [tile it's
// 2 oldest landed, the new 2 STAY IN FLIGHT]; s_barrier; frags+MFMA; s_barrier.
// No vmcnt(0) drain in the loop — the R6 killer.
#define LDS_A  0         // 128KB
#define LDS_B0 131072    // 16KB (PV/PI overlay after the loop)
#define LDS_B1 147456    // 16KB
#define LDS_SZ 163840

__global__ __launch_bounds__(512, 2) void k_argmin_mfma(const float* __restrict__ input,
                                                        const f16* __restrict__ ehlT,
                                                        const float* __restrict__ enorm2,
                                                        int* __restrict__ ind,
                                                        float* __restrict__ out_ind,
                                                        int* __restrict__ counts) {
    __shared__ char lds[LDS_SZ];
    const int tid  = threadIdx.x;
    const int lane = tid & 63;
    const int w    = tid >> 6;        // wave 0..7
    const int wr   = w >> 2;          // 0/1 : rows wr*64..+64
    const int wc   = w & 3;           // 0..3: cols wc*64..+64 within 256-slab
    const int rb   = blockIdx.x * 128;
    const int l15  = lane & 15;
    const int lkh  = lane >> 4;       // 0..3
    const int swa  = (l15 & 7) << 4;
    const int swb  = ((l15 >> 1) & 3) << 4;
    // per-lane global-source offset (f16 units) for B prefetch within a 16-col chunk
    const int slot_log   = (lane & 3) ^ ((lane >> 3) & 3);
    const int gl_laneoff = (lane >> 2) * 512 + slot_log * 8;

    // preload e2 for all 4 slabs -> regs (keep VMEM out of the counted loop)
    float e2a[4][4];
#pragma unroll
    for (int s = 0; s < 4; ++s)
#pragma unroll
        for (int fc = 0; fc < 4; ++fc)
            e2a[s][fc] = enorm2[s * 256 + wc * 64 + fc * 16 + l15];

    // ---- issue B tile 0 prefetch (ct=0, kt=0: koff=0) ----
#pragma unroll
    for (int i = 0; i < 2; i++) {
        int chunkid = w * 2 + i;
        const f16* src = ehlT + (size_t)chunkid * 8192 + gl_laneoff;
        __builtin_amdgcn_global_load_lds((const GLOBAL_AS unsigned*)src,
            (LOCAL_AS unsigned*)(lds + LDS_B0 + chunkid * 1024), 16, 0, 0);
    }

    // ---- stage A once: 128 rows x 256 d fp32 -> hi/lo f16, swizzled ----
#pragma unroll
    for (int it8 = 0; it8 < 4; it8++) {
        int task = tid + 512 * it8;          // 0..2047
        int row = task >> 4, ch = task & 15; // ch = 16-d chunk
        const float4* g = (const float4*)(input + (size_t)(rb + row) * DIM + ch * 16);
        float fv[16];
        *(float4*)(fv + 0)  = g[0];
        *(float4*)(fv + 4)  = g[1];
        *(float4*)(fv + 8)  = g[2];
        *(float4*)(fv + 12) = g[3];
        half8 hh[2], llv[2];
#pragma unroll
        for (int u = 0; u < 2; u++)
#pragma unroll
            for (int e = 0; e < 8; e++) {
                float x = fv[u * 8 + e];
                f16 h = (f16)x;
                hh[u][e]  = h;
                llv[u][e] = (f16)(x - (float)h);
            }
        int rbase = row * 1024;
        int sw = (row & 7) << 4;
        *(half8*)(lds + LDS_A + rbase + (((ch * 2    ) * 16) ^ sw)) = hh[0];
        *(half8*)(lds + LDS_A + rbase + (((ch * 2 + 1) * 16) ^ sw)) = hh[1];
        *(half8*)(lds + LDS_A + rbase + (((32 + ch * 2) * 16) ^ sw)) = llv[0];
        *(half8*)(lds + LDS_A + rbase + (((33 + ch * 2) * 16) ^ sw)) = llv[1];
    }
    __syncthreads();   // full drain ONCE: A staged + B0 landed + e2a in regs

    float bv[16];
    int   bi[16];
#pragma unroll
    for (int q = 0; q < 16; q++) { bv[q] = FLT_MAX; bi[q] = 0x7fffffff; }

    int p = 0;
    for (int ct = 0; ct < 4; ct++) {
        const int cb = ct * 256;
        f32x4 acc[4][4];
#pragma unroll
        for (int fr = 0; fr < 4; fr++)
#pragma unroll
            for (int fc = 0; fc < 4; fc++) acc[fr][fc] = (f32x4){0.f, 0.f, 0.f, 0.f};

        for (int kt = 0; kt < 24; kt++) {
            const int it = ct * 24 + kt;
            // ---- issue next-tile prefetch into the idle buffer; counted wait ----
            if (it < 95) {
                int itn = it + 1;
                int ct2 = itn / 24;
                int kt2 = itn - ct2 * 24;
                int seg2 = kt2 >> 3, kq2 = kt2 & 7;
                int koff2 = ((seg2 == 2) ? 256 : 0) + kq2 * 32;
                const f16* base = ehlT + (size_t)ct2 * 131072 + koff2 + gl_laneoff;
                char* dstb = lds + (p ? LDS_B0 : LDS_B1);
#pragma unroll
                for (int i = 0; i < 2; i++) {
                    int chunkid = w * 2 + i;
                    __builtin_amdgcn_global_load_lds(
                        (const GLOBAL_AS unsigned*)(base + (size_t)chunkid * 8192),
                        (LOCAL_AS unsigned*)(dstb + chunkid * 1024), 16, 0, 0);
                }
                asm volatile("s_waitcnt vmcnt(2)" ::: "memory");  // tile it's 2 landed; new 2 in flight
            } else {
                asm volatile("s_waitcnt vmcnt(0)" ::: "memory");
            }
            __builtin_amdgcn_s_barrier();          // all waves' tile-it chunks visible
            __builtin_amdgcn_sched_barrier(0);     // pin: no hoisting of ds_reads above

            // ---- MFMA on current tile (buf p) ----
            const int seg = kt >> 3, kq = kt & 7;
            const int jslot = ((seg == 1) ? 32 : 0) + kq * 4 + lkh;
            const char* Bb = lds + (p ? LDS_B1 : LDS_B0);
            half8 af[4], bf[4];
#pragma unroll
            for (int f = 0; f < 4; f++) {
                int row = wr * 64 + f * 16 + l15;
                af[f] = *(const half8*)(lds + LDS_A + row * 1024 + ((jslot * 16) ^ swa));
            }
#pragma unroll
            for (int f = 0; f < 4; f++) {
                int col = wc * 64 + f * 16 + l15;
                bf[f] = *(const half8*)(Bb + col * 64 + ((lkh * 16) ^ swb));
            }
            __builtin_amdgcn_s_setprio(1);
#pragma unroll
            for (int fr = 0; fr < 4; fr++)
#pragma unroll
                for (int fc = 0; fc < 4; fc++)
                    acc[fr][fc] = __builtin_amdgcn_mfma_f32_16x16x32_f16(
                        af[fr], bf[fc], acc[fr][fc], 0, 0, 0);
            __builtin_amdgcn_s_setprio(0);

            // ---- slab epilogue: running argmin (registers + e2a only) ----
            if (kt == 23) {
#pragma unroll
                for (int fc = 0; fc < 4; fc++) {
                    int col = cb + wc * 64 + fc * 16 + l15;
                    float e2 = e2a[ct][fc];
#pragma unroll
                    for (int fr = 0; fr < 4; fr++)
#pragma unroll
                        for (int r = 0; r < 4; r++) {
                            float s = fmaf(-2.f, acc[fr][fc][r], e2);
                            int q = fr * 4 + r;
                            if (s < bv[q]) { bv[q] = s; bi[q] = col; }
                        }
                }
            }
            __builtin_amdgcn_s_barrier();   // all waves done reading buf p (no drain!)
            p ^= 1;
        }
    }

    // ---- cross-lane reduce: min over the 16 col-lanes (same lkh group) ----
#pragma unroll
    for (int q = 0; q < 16; q++) {
        float v = bv[q]; int i = bi[q];
#pragma unroll
        for (int m = 1; m <= 8; m <<= 1) {
            float ov = __shfl_xor(v, m, 64);
            int   oi = __shfl_xor(i, m, 64);
            if (ov < v || (ov == v && oi < i)) { v = ov; i = oi; }
        }
        bv[q] = v; bi[q] = i;
    }
    // overlay PV/PI on B0 (final tile was in B1; all B0 reads completed)
    float* PV = (float*)(lds + LDS_B0);          // [128][4]
    int*   PI = (int*)(lds + LDS_B0 + 2048);     // [128][4]
    if (l15 == 0) {
#pragma unroll
        for (int fr = 0; fr < 4; fr++)
#pragma unroll
            for (int r = 0; r < 4; r++) {
                int rrow = wr * 64 + fr * 16 + lkh * 4 + r;
                PV[rrow * 4 + wc] = bv[fr * 4 + r];
                PI[rrow * 4 + wc] = bi[fr * 4 + r];
            }
    }
    __syncthreads();
    if (tid < 128) {
        float best = FLT_MAX; int bidx = 0x7fffffff;
#pragma unroll
        for (int t = 0; t < 4; t++) {
            float v = PV[tid * 4 + t];
            int   i = PI[tid * 4 + t];
            if (v < best || (v == best && i < bidx)) { best = v; bidx = i; }
        }
        ind[rb + tid] = bidx;
        out_ind[rb + tid] = (float)bidx;
        atomicAdd(&counts[bidx], 1);    // fused histogram (wave-coalesced by compiler)
    }
}

// ---------- K2: quantize_st output + per-block diff partials ----------
__global__ __launch_bounds__(256) void k_quant(const float* __restrict__ input,
                                               const float* __restrict__ embedT,
                                               const int* __restrict__ ind,
                                               float* __restrict__ out_q,
                                               float* __restrict__ partials) {
    const int tid = threadIdx.x;
    const unsigned gid = blockIdx.x * 256 + tid;
    float s = 0.f;
#pragma unroll
    for (int j = 0; j < 8; j++) {
        size_t i4 = (size_t)gid + (size_t)j * 524288u;   // 4194304 float4 total
        int row = (int)(i4 >> 6);
        int d4  = (int)(i4 & 63);
        float4 iv = *reinterpret_cast<const float4*>(input + i4 * 4);
        int k = ind[row];
        float4 qv = *reinterpret_cast<const float4*>(embedT + (size_t)k * DIM + d4 * 4);
        float dx = qv.x - iv.x, dy = qv.y - iv.y, dz = qv.z - iv.z, dw = qv.w - iv.w;
        float4 ov;
        ov.x = iv.x + dx; ov.y = iv.y + dy; ov.z = iv.z + dz; ov.w = iv.w + dw;
        *reinterpret_cast<float4*>(out_q + i4 * 4) = ov;
        s += dx * dx + dy * dy + dz * dz + dw * dw;
    }
    __shared__ float red[256];
    red[tid] = s;
    __syncthreads();
    for (int off = 128; off > 0; off >>= 1) {
        if (tid < off) red[tid] += red[tid + off];
        __syncthreads();
    }
    if (tid == 0) partials[blockIdx.x] = red[0];
}

// ---------- K4: diff finalize + scans + ncs, n, cs ----------
__global__ __launch_bounds__(1024) void k_scan(const int* __restrict__ counts,
                                               const float* __restrict__ cluster_size,
                                               const float* __restrict__ qpartials,
                                               int* __restrict__ offsets,
                                               int* __restrict__ cursor,
                                               int* __restrict__ substart,
                                               float* __restrict__ out_ncs,
                                               float* __restrict__ cs,
                                               float* __restrict__ out_diff) {
    __shared__ int sh[NEMB];
    __shared__ float shf[NEMB];
    int tid = threadIdx.x;
    // ---- diff finalize ----
    shf[tid] = qpartials[tid] + qpartials[tid + 1024];
    __syncthreads();
    for (int off = 512; off > 0; off >>= 1) {
        if (tid < off) shf[tid] += shf[tid + off];
        __syncthreads();
    }
    if (tid == 0) out_diff[0] = shf[0] / 16777216.0f;
    __syncthreads();
    // ---- scans ----
    int c = counts[tid];
    sh[tid] = c;
    __syncthreads();
    for (int off = 1; off < NEMB; off <<= 1) {
        int t = (tid >= off) ? sh[tid - off] : 0;
        __syncthreads();
        sh[tid] += t;
        __syncthreads();
    }
    int excl = sh[tid] - c;
    offsets[tid] = excl;
    cursor[tid]  = excl;
    int sc = (c + CH - 1) / CH;
    __syncthreads();
    sh[tid] = sc;
    __syncthreads();
    for (int off = 1; off < NEMB; off <<= 1) {
        int t = (tid >= off) ? sh[tid - off] : 0;
        __syncthreads();
        sh[tid] += t;
        __syncthreads();
    }
    substart[tid] = sh[tid] - sc;
    if (tid == NEMB - 1) substart[NEMB] = sh[tid];
    float ncs = cluster_size[tid] * DECAY + (1.f - DECAY) * (float)c;
    out_ncs[tid] = ncs;
    shf[tid] = ncs;
    __syncthreads();
    for (int off = 512; off > 0; off >>= 1) {
        if (tid < off) shf[tid] += shf[tid + off];
        __syncthreads();
    }
    float n = shf[0];
    cs[tid] = (ncs + EPS) / (n + NEMB * EPS) * n;
}

// ---------- K5: scatter rows by cluster ----------
__global__ __launch_bounds__(256) void k_scatter(const int* __restrict__ ind,
                                                 int* __restrict__ cursor,
                                                 int* __restrict__ sorted) {
    int i = blockIdx.x * 256 + threadIdx.x;
    int k = ind[i];
    int pos = atomicAdd(&cursor[k], 1);
    sorted[pos] = i;
}

// ---------- K6a: balanced partial sums. block = one 64-row sub-chunk ----------
__global__ __launch_bounds__(256) void k_psum(const float* __restrict__ input,
                                              const int* __restrict__ sorted,
                                              const int* __restrict__ counts,
                                              const int* __restrict__ offsets,
                                              const int* __restrict__ substart,
                                              float* __restrict__ partial) {
    const int b = blockIdx.x;
    if (b >= substart[NEMB]) return;
    int lo = 0, hi = NEMB;
    while (hi - lo > 1) {
        int mid = (lo + hi) >> 1;
        if (substart[mid] <= b) lo = mid; else hi = mid;
    }
    const int k     = lo;
    const int chunk = b - substart[k];
    const int cnt   = counts[k];
    const int base  = offsets[k] + chunk * CH;
    const int lim   = min(CH, cnt - chunk * CH);
    const int d     = threadIdx.x;
    float s = 0.f;
    for (int i = 0; i < lim; i++) {
        int row = sorted[base + i];
        s += input[(size_t)row * DIM + d];
    }
    partial[(size_t)b * DIM + d] = s;
}

// ---------- K6b: per-cluster combine (fixed order) + EMA + new_embed ----------
__global__ __launch_bounds__(256) void k_ema(const float* __restrict__ partial,
                                             const float* __restrict__ embed_avg,
                                             const int* __restrict__ substart,
                                             const float* __restrict__ cs,
                                             float* __restrict__ out_navg,
                                             float* __restrict__ out_nembed) {
    const int d = blockIdx.x;
    const int t = threadIdx.x;
#pragma unroll
    for (int i = 0; i < 4; i++) {
        int k = t + 256 * i;
        int s0 = substart[k], s1 = substart[k + 1];
        float s = 0.f;
        for (int sub = s0; sub < s1; sub++)
            s += partial[(size_t)sub * DIM + d];
        float navg = embed_avg[(size_t)d * NEMB + k] * (DECAY * DECAY) + (1.f - DECAY) * s;
        out_navg[(size_t)d * NEMB + k] = navg;
        out_nembed[(size_t)d * NEMB + k] = navg / cs[k];
    }
}

extern "C" void kernel_launch(void* const* d_in, const int* in_sizes, int n_in,
                              void* d_out, int out_size, void* d_ws, size_t ws_size,
                              hipStream_t stream) {
    const float* input        = (const float*)d_in[0];
    const float* embed        = (const float*)d_in[1];
    const float* cluster_size = (const float*)d_in[2];
    const float* embed_avg    = (const float*)d_in[3];

    float* out        = (float*)d_out;
    float* out_q      = out;                       // 16777216
    float* out_diff   = out + 16777216;            // 1
    float* out_ind    = out + 16777217;            // 65536
    float* out_ncs    = out + 16842753;            // 1024
    float* out_navg   = out + 16843777;            // 262144
    float* out_nembed = out + 17105921;            // 262144

    char* ws = (char*)d_ws;
    size_t o = 0;
    int*   w_ind      = (int*)(ws + o);   o += (size_t)NROWS * 4;
    float* w_embedT   = (float*)(ws + o); o += (size_t)DIM * NEMB * 4;
    float* w_enorm    = (float*)(ws + o); o += NEMB * 4;
    int*   w_counts   = (int*)(ws + o);   o += NEMB * 4;
    int*   w_offsets  = (int*)(ws + o);   o += NEMB * 4;
    int*   w_cursor   = (int*)(ws + o);   o += NEMB * 4;
    float* w_cs       = (float*)(ws + o); o += NEMB * 4;
    float* w_partials = (float*)(ws + o); o += 2048 * 4;
    int*   w_sorted   = (int*)(ws + o);   o += (size_t)NROWS * 4;
    int*   w_substart = (int*)(ws + o);   o += (NEMB + 4) * 4;
    float* w_partial  = (float*)(ws + o); o += (size_t)MAXSUB * DIM * 4;
    f16*   w_ehlT     = (f16*)(ws + o);   o += (size_t)NEMB * 512 * 2;

    k_enorm<<<16, 256, 0, stream>>>(embed, w_enorm, w_counts);
    k_prep<<<dim3(32, 8), dim3(32, 8), 0, stream>>>(embed, w_embedT, w_ehlT);
    k_argmin_mfma<<<NROWS / 128, 512, 0, stream>>>(input, w_ehlT, w_enorm,
                                                   w_ind, out_ind, w_counts);
    k_quant<<<2048, 256, 0, stream>>>(input, w_embedT, w_ind, out_q, w_partials);
    k_scan<<<1, 1024, 0, stream>>>(w_counts, cluster_size, w_partials, w_offsets,
                                   w_cursor, w_substart, out_ncs, w_cs, out_diff);
    k_scatter<<<NROWS / 256, 256, 0, stream>>>(w_ind, w_cursor, w_sorted);
    k_psum<<<MAXSUB, 256, 0, stream>>>(input, w_sorted, w_counts, w_offsets,
                                       w_substart, w_partial);
    k_ema<<<DIM, 256, 0, stream>>>(w_partial, embed_avg, w_substart, w_cs,
                                   out_navg, out_nembed);
}